// Round 6
// baseline (533.488 us; speedup 1.0000x reference)
//
#include <hip/hip_runtime.h>
#include <cstdint>

// Problem constants
#define BB 4
#define LL 1024
#define DM 512
#define DI 1024
#define DS 16
#define DTR 32
#define NX 64          // DTR + 2*DS
#define MROWS 4096     // B*L
#define CH 32          // scan chunk length
#define NCH 32         // LL / CH
#define PQLIN (BB * NCH * DI * DS)   // 2,097,152 linear elems each for P and Q

typedef unsigned short u16;
typedef __attribute__((ext_vector_type(8))) short bf16x8;
typedef __attribute__((ext_vector_type(4))) float f32x4;

__device__ __forceinline__ float bf2f(u16 u) {
    union { unsigned int i; float f; } v;
    v.i = ((unsigned int)u) << 16;
    return v.f;
}
__device__ __forceinline__ u16 f2bf(float f) {
    union { float f; unsigned u; } v;
    v.f = f;
    return (u16)((v.u + 0x7fffu + ((v.u >> 16) & 1u)) >> 16);
}

// P/Q live in the dead xin half of xzb (cols 0..1023; rows 0..4095).
__device__ __forceinline__ size_t hole(size_t i) {
    return ((i >> 10) << 11) | (i & 1023);
}

// ---------------------------------------------------------------------------
// Weight transpose+cast: src[K][N] f32 -> dst[N][K] bf16. z selects weight.
__global__ __launch_bounds__(256) void wtrans(
    const float* __restrict__ Wi, const float* __restrict__ Wo,
    const float* __restrict__ Wx, const float* __restrict__ Wdt,
    u16* __restrict__ WiT, u16* __restrict__ WoT,
    u16* __restrict__ WxT, u16* __restrict__ WdtT)
{
    int z = blockIdx.z;
    int K, N; const float* src; u16* dst;
    if (z == 0)      { K = 512;  N = 2048; src = Wi;  dst = WiT; }
    else if (z == 1) { K = 1024; N = 512;  src = Wo;  dst = WoT; }
    else if (z == 2) { K = 1024; N = 64;   src = Wx;  dst = WxT; }
    else             { K = 32;   N = 1024; src = Wdt; dst = WdtT; }
    int n0 = blockIdx.x * 64, k0 = blockIdx.y * 64;
    if (n0 >= N || k0 >= K) return;
    __shared__ u16 tile[64][65];
    int tn = threadIdx.x & 63, tr = threadIdx.x >> 6;
    for (int r = tr; r < 64; r += 4) {
        int k = k0 + r;
        if (k < K && n0 + tn < N)
            tile[r][tn] = f2bf(src[(size_t)k * N + n0 + tn]);
    }
    __syncthreads();
    for (int r = tr; r < 64; r += 4) {
        int n = n0 + r, k = k0 + tn;
        if (n < N && k < K)
            dst[(size_t)n * K + k] = tile[tn][r];
    }
}

// ---------------------------------------------------------------------------
// cast f32 -> bf16 (x input)
__global__ void cast_bf16(const float4* __restrict__ in, ushort4* __restrict__ out, int n4) {
    int i = blockIdx.x * 256 + threadIdx.x;
    if (i < n4) {
        float4 v = in[i];
        out[i] = make_ushort4(f2bf(v.x), f2bf(v.y), f2bf(v.z), f2bf(v.w));
    }
}

// ---------------------------------------------------------------------------
// Unified MFMA bf16 GEMM. A[M][lda] bf16, W[N][ldb] bf16 (pre-transposed),
// C f32 (ldc). Tile TM x TN, 4 waves (2x2), BK=32, XOR-swizzled LDS (layout
// verified rounds 4-5). Split-K via blockIdx.z (partials to distinct slices).
// EP: 0 plain store, 1 softplus(acc + bias[col]).
template <int TM, int TN, int EP>
__global__ __launch_bounds__(256) void gemm_mfma(
    const u16* __restrict__ A, const u16* __restrict__ W, float* __restrict__ C,
    int lda, int ldb, int ldc, int kchunk, const float* __restrict__ bias)
{
    constexpr int NI = TM / 32, NJ = TN / 32;
    constexpr int SLOTS = (TM + TN) * 4 / 256;
    __shared__ char lds[(TM + TN) * 64];
    const int tid = threadIdx.x;
    const int lane = tid & 63;
    const int wave = tid >> 6;
    const int wm = wave >> 1, wn = wave & 1;
    const int lm = lane & 15, quad = lane >> 4;
    const int row0 = blockIdx.y * TM, col0 = blockIdx.x * TN;
    const int kstart = blockIdx.z * kchunk;
    float* Cz = C + (size_t)blockIdx.z * (size_t)gridDim.y * TM * ldc;

    const u16* sp[SLOTS];
    int lo[SLOTS];
#pragma unroll
    for (int s = 0; s < SLOTS; ++s) {
        int slot = s * 256 + tid;
        int row = slot >> 2, g = slot & 3;
        if (row < TM) sp[s] = A + (size_t)(row0 + row) * lda + kstart + g * 8;
        else          sp[s] = W + (size_t)(col0 + row - TM) * ldb + kstart + g * 8;
        lo[s] = row * 64 + ((g ^ (row & 3)) << 4);
    }

    f32x4 acc[NI][NJ];
#pragma unroll
    for (int i = 0; i < NI; ++i)
#pragma unroll
        for (int j = 0; j < NJ; ++j) acc[i][j] = (f32x4){0.f, 0.f, 0.f, 0.f};

    for (int k0 = 0; k0 < kchunk; k0 += 32) {
        uint4 v[SLOTS];
#pragma unroll
        for (int s = 0; s < SLOTS; ++s) {
            v[s] = *(const uint4*)sp[s];
            sp[s] += 32;
        }
        __syncthreads();
#pragma unroll
        for (int s = 0; s < SLOTS; ++s)
            *(uint4*)(lds + lo[s]) = v[s];
        __syncthreads();

        bf16x8 af[NI], bf[NJ];
#pragma unroll
        for (int i = 0; i < NI; ++i) {
            int r = wm * (TM / 2) + i * 16 + lm;
            af[i] = *(const bf16x8*)(lds + r * 64 + ((quad ^ (lm & 3)) << 4));
        }
#pragma unroll
        for (int j = 0; j < NJ; ++j) {
            int r = TM + wn * (TN / 2) + j * 16 + lm;
            bf[j] = *(const bf16x8*)(lds + r * 64 + ((quad ^ (lm & 3)) << 4));
        }
#pragma unroll
        for (int i = 0; i < NI; ++i)
#pragma unroll
            for (int j = 0; j < NJ; ++j)
                acc[i][j] = __builtin_amdgcn_mfma_f32_16x16x32_bf16(
                    af[i], bf[j], acc[i][j], 0, 0, 0);
    }

#pragma unroll
    for (int i = 0; i < NI; ++i) {
#pragma unroll
        for (int j = 0; j < NJ; ++j) {
#pragma unroll
            for (int r = 0; r < 4; ++r) {
                int row = row0 + wm * (TM / 2) + i * 16 + quad * 4 + r;
                int col = col0 + wn * (TN / 2) + j * 16 + lm;
                float v = acc[i][j][r];
                if (EP == 1) {
                    v += bias[col];
                    v = fmaxf(v, 0.f) + log1pf(__expf(-fabsf(v)));
                }
                Cz[(size_t)row * ldc + col] = v;
            }
        }
    }
}

// ---------------------------------------------------------------------------
// reduce split-K partials: dbc = sum_z pxp[z]; also emit bf16 copy for dt_proj
__global__ __launch_bounds__(256) void reduce_dbc(
    const float4* __restrict__ px, float4* __restrict__ dbc, ushort4* __restrict__ dbcb)
{
    int i = blockIdx.x * 256 + threadIdx.x;   // 65536 float4s
    float4 s = px[i];
#pragma unroll
    for (int z = 1; z < 8; ++z) {
        float4 v = px[(size_t)z * 65536 + i];
        s.x += v.x; s.y += v.y; s.z += v.z; s.w += v.w;
    }
    dbc[i] = s;
    dbcb[i] = make_ushort4(f2bf(s.x), f2bf(s.y), f2bf(s.z), f2bf(s.w));
}

// ---------------------------------------------------------------------------
// depthwise causal conv (kernel 4) + bias + SiLU -> xs (bf16)
__global__ void conv_silu_kernel(const float* __restrict__ xz,
                                 const float* __restrict__ cw, const float* __restrict__ cb,
                                 u16* __restrict__ xs)
{
    int idx = blockIdx.x * blockDim.x + threadIdx.x;
    int d = idx & (DI - 1);
    int bt = idx >> 10;
    int t = bt & (LL - 1);
    float acc = cb[d];
#pragma unroll
    for (int k = 0; k < 4; ++k) {
        int tt = t - 3 + k;
        if (tt >= 0) acc += xz[(size_t)(bt - 3 + k) * 2048 + d] * cw[d * 4 + k];
    }
    xs[idx] = f2bf(acc / (1.f + __expf(-acc)));
}

// ---------------------------------------------------------------------------
// Chunk-parallel scan, register-state (one thread = all 16 states of (b,chunk,d))
__global__ __launch_bounds__(256) void scan_pass1(
    const float* __restrict__ delta, const u16* __restrict__ xs,
    const float* __restrict__ dbc, const float* __restrict__ A_log,
    float* __restrict__ PQ)
{
    const int dgrp = blockIdx.x & 3;
    const int chunk = (blockIdx.x >> 2) & (NCH - 1);
    const int b = blockIdx.x >> 7;
    const int d = dgrp * 256 + threadIdx.x;
    const int t0 = b * LL + chunk * CH;

    __shared__ float sB[CH][DS];
    {
        int i = threadIdx.x;
        int row = i >> 3, col = (i & 7) * 2;
        float2 v = *(const float2*)(dbc + (size_t)(t0 + row) * NX + DTR + col);
        sB[row][col] = v.x; sB[row][col + 1] = v.y;
    }
    float An[DS];
#pragma unroll
    for (int n = 0; n < DS; ++n) An[n] = -__expf(A_log[d * DS + n]);
    __syncthreads();

    float P[DS], h[DS];
#pragma unroll
    for (int n = 0; n < DS; ++n) { P[n] = 1.f; h[n] = 0.f; }

    const float* dp = delta + (size_t)t0 * DI + d;
    const u16* xp = xs + (size_t)t0 * DI + d;
#pragma unroll 4
    for (int t = 0; t < CH; ++t) {
        float dlt = dp[t * DI];
        float du = dlt * bf2f(xp[t * DI]);
#pragma unroll
        for (int n = 0; n < DS; ++n) {
            float dA = __expf(dlt * An[n]);
            P[n] *= dA;
            h[n] = fmaf(dA, h[n], du * sB[t][n]);
        }
    }
    size_t base = ((size_t)(b * NCH + chunk) * DI + d) * DS;
    float4* Pp = (float4*)(PQ + hole(base));
    float4* Qp = (float4*)(PQ + hole(base + PQLIN));
#pragma unroll
    for (int g = 0; g < 4; ++g) {
        Pp[g] = make_float4(P[g * 4], P[g * 4 + 1], P[g * 4 + 2], P[g * 4 + 3]);
        Qp[g] = make_float4(h[g * 4], h[g * 4 + 1], h[g * 4 + 2], h[g * 4 + 3]);
    }
}

__global__ __launch_bounds__(256) void scan_pass2(float* __restrict__ PQ)
{
    int tid = blockIdx.x * 256 + threadIdx.x;
    int n = tid & 15;
    int d = (tid >> 4) & (DI - 1);
    int b = tid >> 14;
    float carry = 0.f;
    for (int c = 0; c < NCH; ++c) {
        size_t i = ((size_t)(b * NCH + c) * DI + d) * DS + n;
        float Pv = PQ[hole(i)];
        float Qv = PQ[hole(i + PQLIN)];
        PQ[hole(i)] = carry;
        carry = fmaf(Pv, carry, Qv);
    }
}

// pass3: re-run from H_in; y = sum_n h_n C_n + D-skip, silu(z) gate -> ybf (bf16)
__global__ __launch_bounds__(256) void scan_pass3(
    const float* __restrict__ delta, const u16* __restrict__ xs,
    const float* __restrict__ dbc, const float* __restrict__ xz,
    const float* __restrict__ A_log, const float* __restrict__ Dsk,
    const float* __restrict__ PQ, u16* __restrict__ yb)
{
    const int dgrp = blockIdx.x & 3;
    const int chunk = (blockIdx.x >> 2) & (NCH - 1);
    const int b = blockIdx.x >> 7;
    const int d = dgrp * 256 + threadIdx.x;
    const int t0 = b * LL + chunk * CH;

    __shared__ float sBC[CH][32];   // cols 0..15 = B, 16..31 = C
    {
        int i = threadIdx.x;
        int row = i >> 3, col = (i & 7) * 4;
        float4 v = *(const float4*)(dbc + (size_t)(t0 + row) * NX + DTR + col);
        *(float4*)&sBC[row][col] = v;
    }
    float An[DS];
#pragma unroll
    for (int n = 0; n < DS; ++n) An[n] = -__expf(A_log[d * DS + n]);
    const float Dd = Dsk[d];

    float h[DS];
    {
        size_t base = ((size_t)(b * NCH + chunk) * DI + d) * DS;
        const float4* Hp = (const float4*)(PQ + hole(base));
#pragma unroll
        for (int g = 0; g < 4; ++g) {
            float4 v = Hp[g];
            h[g * 4] = v.x; h[g * 4 + 1] = v.y; h[g * 4 + 2] = v.z; h[g * 4 + 3] = v.w;
        }
    }
    __syncthreads();

    const float* dp = delta + (size_t)t0 * DI + d;
    const u16* xp = xs + (size_t)t0 * DI + d;
    const float* zp = xz + (size_t)t0 * 2048 + DI + d;
    u16* yp = yb + (size_t)t0 * DI + d;

#pragma unroll 4
    for (int t = 0; t < CH; ++t) {
        float dlt = dp[t * DI];
        float xv  = bf2f(xp[t * DI]);
        float zv  = zp[t * 2048];
        float du = dlt * xv;
        float y = 0.f;
#pragma unroll
        for (int n = 0; n < DS; ++n) {
            float dA = __expf(dlt * An[n]);
            h[n] = fmaf(dA, h[n], du * sBC[t][n]);
            y = fmaf(h[n], sBC[t][DS + n], y);
        }
        y += xv * Dd;
        float sz = zv / (1.f + __expf(-zv));
        yp[t * DI] = f2bf(y * sz);
    }
}

// ---------------------------------------------------------------------------
// residual add + LayerNorm; writes f32 hout; optionally bf16 copy (next GEMM A)
__global__ __launch_bounds__(512) void ln_kernel(
    const float* __restrict__ o, const float* __restrict__ hprev,
    const float* __restrict__ g, const float* __restrict__ bta,
    float* __restrict__ hout, u16* __restrict__ hbf, int wb)
{
    int row = blockIdx.x, c = threadIdx.x;
    size_t off = (size_t)row * DM + c;
    float v = o[off] + hprev[off];
    float s1 = v, s2 = v * v;
#pragma unroll
    for (int m = 32; m >= 1; m >>= 1) {
        s1 += __shfl_xor(s1, m);
        s2 += __shfl_xor(s2, m);
    }
    __shared__ float r1[8], r2[8];
    __shared__ float stats[2];
    int w = c >> 6;
    if ((c & 63) == 0) { r1[w] = s1; r2[w] = s2; }
    __syncthreads();
    if (c == 0) {
        float a = 0.f, q = 0.f;
        for (int i = 0; i < 8; ++i) { a += r1[i]; q += r2[i]; }
        float mean = a / (float)DM;
        float var = q / (float)DM - mean * mean;
        stats[0] = mean;
        stats[1] = rsqrtf(var + 1e-5f);
    }
    __syncthreads();
    float res = (v - stats[0]) * stats[1] * g[c] + bta[c];
    hout[off] = res;
    if (wb) hbf[off] = f2bf(res);
}

// ---------------------------------------------------------------------------
extern "C" void kernel_launch(void* const* d_in, const int* in_sizes, int n_in,
                              void* d_out, int out_size, void* d_ws, size_t ws_size,
                              hipStream_t stream)
{
    const float* x    = (const float*)d_in[0];
    const float* Wi   = (const float*)d_in[1];
    const float* cw   = (const float*)d_in[2];
    const float* cb   = (const float*)d_in[3];
    const float* Wx   = (const float*)d_in[4];
    const float* Wdt  = (const float*)d_in[5];
    const float* bdt  = (const float*)d_in[6];
    const float* Alog = (const float*)d_in[7];
    const float* Dsk  = (const float*)d_in[8];
    const float* Wo   = (const float*)d_in[9];
    const float* lng  = (const float*)d_in[10];
    const float* lnb  = (const float*)d_in[11];

    float* ws   = (float*)d_ws;
    float* h    = ws;                        // 2M floats
    float* xzb  = h + 2097152;               // 8M (xin half doubles as P/Q)
    float* dlt  = xzb + 8388608;             // 4M
    float* ob   = dlt + 4194304;             // 2M
    float* dbc  = ob + 2097152;              // 262144
    float* pxp  = dbc + 262144;              // 2M (8 x 4096 x 64)
    u16*  abf   = (u16*)(pxp + 2097152);     // 4,194,304 u16 (xbf/hbf/ybf)
    u16*  xsbf  = abf + 4194304;             // 4,194,304 u16
    u16*  dbcb  = xsbf + 4194304;            // 262,144 u16
    u16*  WiT   = dbcb + 262144;             // 1,048,576 u16
    u16*  WoT   = WiT + 1048576;             // 524,288 u16
    u16*  WxT   = WoT + 524288;              // 65,536 u16
    u16*  WdtT  = WxT + 65536;               // 32,768 u16

    // xbf = bf16(x)
    cast_bf16<<<2048, 256, 0, stream>>>((const float4*)x, (ushort4*)abf, 524288);

    for (int l = 0; l < 2; ++l) {
        const float* hin = (l == 0) ? x : h;

        // transpose+cast this layer's weights to [N][K] bf16
        wtrans<<<dim3(32, 16, 4), 256, 0, stream>>>(
            Wi + (size_t)l * 512 * 2048, Wo + (size_t)l * 1024 * 512,
            Wx + (size_t)l * 1024 * 64, Wdt + (size_t)l * 32 * 1024,
            WiT, WoT, WxT, WdtT);

        // xz = h @ Wi  (4096 x 2048, K=512)
        gemm_mfma<128, 128, 0><<<dim3(16, 32, 1), 256, 0, stream>>>(
            abf, WiT, xzb, 512, 512, 2048, 512, nullptr);

        // xs = silu(conv(xin) + cb)  -> bf16
        conv_silu_kernel<<<MROWS * DI / 256, 256, 0, stream>>>(
            xzb, cw + (size_t)l * DI * 4, cb + (size_t)l * DI, xsbf);

        // dbc partials = xs @ Wx  (split-K=8, deterministic)
        gemm_mfma<128, 64, 0><<<dim3(1, 32, 8), 256, 0, stream>>>(
            xsbf, WxT, pxp, 1024, 1024, 64, 128, nullptr);
        reduce_dbc<<<256, 256, 0, stream>>>(
            (const float4*)pxp, (float4*)dbc, (ushort4*)dbcb);

        // delta = softplus(dbc[:, :32] @ Wdt + bdt)  (K=32, one MFMA k-iter)
        gemm_mfma<128, 128, 1><<<dim3(8, 32, 1), 256, 0, stream>>>(
            dbcb, WdtT, dlt, 64, 32, 1024, 32, bdt + (size_t)l * DI);

        // chunk-parallel selective scan -> ybf (bf16, into abf)
        scan_pass1<<<BB * NCH * 4, 256, 0, stream>>>(
            dlt, xsbf, dbc, Alog + (size_t)l * DI * DS, xzb);
        scan_pass2<<<256, 256, 0, stream>>>(xzb);
        scan_pass3<<<BB * NCH * 4, 256, 0, stream>>>(
            dlt, xsbf, dbc, xzb, Alog + (size_t)l * DI * DS, Dsk + (size_t)l * DI,
            xzb, abf);

        // o = y @ Wo  (4096 x 512, K=1024)
        gemm_mfma<64, 128, 0><<<dim3(4, 64, 1), 256, 0, stream>>>(
            abf, WoT, ob, 1024, 1024, 512, 1024, nullptr);

        // h = LN(o + hin); l=0 also writes bf16 h for next layer; l=1 -> d_out
        ln_kernel<<<MROWS, 512, 0, stream>>>(
            ob, hin, lng + (size_t)l * DM, lnb + (size_t)l * DM,
            (l == 1) ? (float*)d_out : h, abf, l == 0);
    }
}

// Round 7
// 501.948 us; speedup vs baseline: 1.0628x; 1.0628x over previous
//
#include <hip/hip_runtime.h>
#include <cstdint>

// Problem constants
#define BB 4
#define LL 1024
#define DM 512
#define DI 1024
#define DS 16
#define DTR 32
#define NX 64          // DTR + 2*DS
#define MROWS 4096     // B*L
#define CH 32          // scan chunk length
#define NCH 32         // LL / CH

typedef unsigned short u16;
typedef __attribute__((ext_vector_type(8))) short bf16x8;
typedef __attribute__((ext_vector_type(4))) float f32x4;

__device__ __forceinline__ float bf2f(u16 u) {
    union { unsigned int i; float f; } v;
    v.i = ((unsigned int)u) << 16;
    return v.f;
}
__device__ __forceinline__ u16 f2bf(float f) {
    union { float f; unsigned u; } v;
    v.f = f;
    return (u16)((v.u + 0x7fffu + ((v.u >> 16) & 1u)) >> 16);
}

// ---------------------------------------------------------------------------
// Weight transpose+cast: src[K][N] f32 -> dst[N][K] bf16. z = layer*4 + which.
__global__ __launch_bounds__(256) void wtrans(
    const float* __restrict__ Wi, const float* __restrict__ Wo,
    const float* __restrict__ Wx, const float* __restrict__ Wdt,
    u16* __restrict__ WiT, u16* __restrict__ WoT,
    u16* __restrict__ WxT, u16* __restrict__ WdtT)
{
    int l = blockIdx.z >> 2, w = blockIdx.z & 3;
    int K, N; const float* src; u16* dst;
    if (w == 0)      { K = 512;  N = 2048; src = Wi + (size_t)l * 512 * 2048;  dst = WiT + (size_t)l * 2048 * 512; }
    else if (w == 1) { K = 1024; N = 512;  src = Wo + (size_t)l * 1024 * 512;  dst = WoT + (size_t)l * 512 * 1024; }
    else if (w == 2) { K = 1024; N = 64;   src = Wx + (size_t)l * 1024 * 64;   dst = WxT + (size_t)l * 64 * 1024; }
    else             { K = 32;   N = 1024; src = Wdt + (size_t)l * 32 * 1024;  dst = WdtT + (size_t)l * 1024 * 32; }
    int n0 = blockIdx.x * 64, k0 = blockIdx.y * 64;
    if (n0 >= N || k0 >= K) return;
    __shared__ u16 tile[64][65];
    int tn = threadIdx.x & 63, tr = threadIdx.x >> 6;
    for (int r = tr; r < 64; r += 4) {
        int k = k0 + r;
        if (k < K && n0 + tn < N)
            tile[r][tn] = f2bf(src[(size_t)k * N + n0 + tn]);
    }
    __syncthreads();
    for (int r = tr; r < 64; r += 4) {
        int n = n0 + r, k = k0 + tn;
        if (n < N && k < K)
            dst[(size_t)n * K + k] = tile[tn][r];
    }
}

// ---------------------------------------------------------------------------
// cast f32 -> bf16 (x input)
__global__ void cast_bf16(const float4* __restrict__ in, ushort4* __restrict__ out, int n4) {
    int i = blockIdx.x * 256 + threadIdx.x;
    if (i < n4) {
        float4 v = in[i];
        out[i] = make_ushort4(f2bf(v.x), f2bf(v.y), f2bf(v.z), f2bf(v.w));
    }
}

// ---------------------------------------------------------------------------
// Software-pipelined MFMA bf16 GEMM. A[M][lda] bf16, W[N][ldb] bf16 (pre-
// transposed), C typed CT (float or u16/bf16). Tile TM x TN, 4 waves (2x2),
// BK=32, XOR-swizzled LDS (layout verified rounds 4-6). Register prefetch of
// the next k-iter keeps loads in flight across the MFMA stage.
// SP: 1 = softplus(acc + bias[col]) epilogue. Split-K via blockIdx.z.
template <int TM, int TN, int SP, typename CT>
__global__ __launch_bounds__(256) void gemm_pipe(
    const u16* __restrict__ A, const u16* __restrict__ W, CT* __restrict__ C,
    int lda, int ldb, int ldc, int kchunk, const float* __restrict__ bias)
{
    constexpr int NI = TM / 32, NJ = TN / 32;
    constexpr int SLOTS = (TM + TN) * 4 / 256;
    __shared__ char lds[(TM + TN) * 64];
    const int tid = threadIdx.x;
    const int lane = tid & 63;
    const int wave = tid >> 6;
    const int wm = wave >> 1, wn = wave & 1;
    const int lm = lane & 15, quad = lane >> 4;
    const int row0 = blockIdx.y * TM, col0 = blockIdx.x * TN;
    const int kstart = blockIdx.z * kchunk;
    CT* Cz = C + (size_t)blockIdx.z * (size_t)(gridDim.y * TM) * ldc;

    const u16* sp[SLOTS];
    int lo[SLOTS];
#pragma unroll
    for (int s = 0; s < SLOTS; ++s) {
        int slot = s * 256 + tid;
        int row = slot >> 2, g = slot & 3;
        if (row < TM) sp[s] = A + (size_t)(row0 + row) * lda + kstart + g * 8;
        else          sp[s] = W + (size_t)(col0 + row - TM) * ldb + kstart + g * 8;
        lo[s] = row * 64 + ((g ^ (row & 3)) << 4);
    }

    f32x4 acc[NI][NJ];
#pragma unroll
    for (int i = 0; i < NI; ++i)
#pragma unroll
        for (int j = 0; j < NJ; ++j) acc[i][j] = (f32x4){0.f, 0.f, 0.f, 0.f};

    uint4 v[SLOTS];
#pragma unroll
    for (int s = 0; s < SLOTS; ++s) {
        v[s] = *(const uint4*)sp[s];
        sp[s] += 32;
    }

    for (int k0 = 0; k0 < kchunk; k0 += 32) {
        __syncthreads();   // previous iteration's frag reads complete
#pragma unroll
        for (int s = 0; s < SLOTS; ++s)
            *(uint4*)(lds + lo[s]) = v[s];
        if (k0 + 32 < kchunk) {
#pragma unroll
            for (int s = 0; s < SLOTS; ++s) {
                v[s] = *(const uint4*)sp[s];   // prefetch: in flight through MFMA
                sp[s] += 32;
            }
        }
        __syncthreads();

        bf16x8 af[NI], bf[NJ];
#pragma unroll
        for (int i = 0; i < NI; ++i) {
            int r = wm * (TM / 2) + i * 16 + lm;
            af[i] = *(const bf16x8*)(lds + r * 64 + ((quad ^ (lm & 3)) << 4));
        }
#pragma unroll
        for (int j = 0; j < NJ; ++j) {
            int r = TM + wn * (TN / 2) + j * 16 + lm;
            bf[j] = *(const bf16x8*)(lds + r * 64 + ((quad ^ (lm & 3)) << 4));
        }
#pragma unroll
        for (int i = 0; i < NI; ++i)
#pragma unroll
            for (int j = 0; j < NJ; ++j)
                acc[i][j] = __builtin_amdgcn_mfma_f32_16x16x32_bf16(
                    af[i], bf[j], acc[i][j], 0, 0, 0);
    }

#pragma unroll
    for (int i = 0; i < NI; ++i) {
#pragma unroll
        for (int j = 0; j < NJ; ++j) {
#pragma unroll
            for (int r = 0; r < 4; ++r) {
                int row = row0 + wm * (TM / 2) + i * 16 + quad * 4 + r;
                int col = col0 + wn * (TN / 2) + j * 16 + lm;
                float val = acc[i][j][r];
                if (SP) {
                    val += bias[col];
                    val = fmaxf(val, 0.f) + log1pf(__expf(-fabsf(val)));
                }
                if (sizeof(CT) == 2)
                    ((u16*)Cz)[(size_t)row * ldc + col] = f2bf(val);
                else
                    ((float*)Cz)[(size_t)row * ldc + col] = val;
            }
        }
    }
}

// ---------------------------------------------------------------------------
// reduce split-K partials: dbc = sum_z pxp[z]; also emit bf16 copy for dt_proj
__global__ __launch_bounds__(256) void reduce_dbc(
    const float4* __restrict__ px, float4* __restrict__ dbc, ushort4* __restrict__ dbcb)
{
    int i = blockIdx.x * 256 + threadIdx.x;   // 65536 float4s
    float4 s = px[i];
#pragma unroll
    for (int z = 1; z < 8; ++z) {
        float4 v = px[(size_t)z * 65536 + i];
        s.x += v.x; s.y += v.y; s.z += v.z; s.w += v.w;
    }
    dbc[i] = s;
    dbcb[i] = make_ushort4(f2bf(s.x), f2bf(s.y), f2bf(s.z), f2bf(s.w));
}

// ---------------------------------------------------------------------------
// depthwise causal conv (kernel 4) + bias + SiLU; bf16 in (xz), bf16 out (xs)
// one thread = 4 consecutive d
__global__ void conv_silu_kernel(const u16* __restrict__ xz,
                                 const float* __restrict__ cw, const float* __restrict__ cb,
                                 ushort4* __restrict__ xs)
{
    int i = blockIdx.x * 256 + threadIdx.x;   // 0 .. 1M-1 (d-quads)
    int d = (i & 255) * 4;
    int bt = i >> 8;
    int t = bt & (LL - 1);
    float a0 = cb[d], a1 = cb[d + 1], a2 = cb[d + 2], a3 = cb[d + 3];
    float4 w0 = *(const float4*)(cw + (size_t)d * 4);
    float4 w1 = *(const float4*)(cw + (size_t)(d + 1) * 4);
    float4 w2 = *(const float4*)(cw + (size_t)(d + 2) * 4);
    float4 w3 = *(const float4*)(cw + (size_t)(d + 3) * 4);
    const float* wp0 = (const float*)&w0;
    const float* wp1 = (const float*)&w1;
    const float* wp2 = (const float*)&w2;
    const float* wp3 = (const float*)&w3;
#pragma unroll
    for (int k = 0; k < 4; ++k) {
        int tt = t - 3 + k;
        if (tt >= 0) {
            ushort4 xv = *(const ushort4*)(xz + (size_t)(bt - 3 + k) * 2048 + d);
            a0 = fmaf(bf2f(xv.x), wp0[k], a0);
            a1 = fmaf(bf2f(xv.y), wp1[k], a1);
            a2 = fmaf(bf2f(xv.z), wp2[k], a2);
            a3 = fmaf(bf2f(xv.w), wp3[k], a3);
        }
    }
    xs[i] = make_ushort4(
        f2bf(a0 / (1.f + __expf(-a0))), f2bf(a1 / (1.f + __expf(-a1))),
        f2bf(a2 / (1.f + __expf(-a2))), f2bf(a3 / (1.f + __expf(-a3))));
}

// ---------------------------------------------------------------------------
// Chunk-parallel scan, register-state (one thread = all 16 states of (b,chunk,d))
__global__ __launch_bounds__(256) void scan_pass1(
    const u16* __restrict__ delta, const u16* __restrict__ xs,
    const float* __restrict__ dbc, const float* __restrict__ A_log,
    float* __restrict__ P, float* __restrict__ Q)
{
    const int dgrp = blockIdx.x & 3;
    const int chunk = (blockIdx.x >> 2) & (NCH - 1);
    const int b = blockIdx.x >> 7;
    const int d = dgrp * 256 + threadIdx.x;
    const int t0 = b * LL + chunk * CH;

    __shared__ float sB[CH][DS];
    {
        int i = threadIdx.x;
        int row = i >> 3, col = (i & 7) * 2;
        float2 v = *(const float2*)(dbc + (size_t)(t0 + row) * NX + DTR + col);
        sB[row][col] = v.x; sB[row][col + 1] = v.y;
    }
    float An[DS];
#pragma unroll
    for (int n = 0; n < DS; ++n) An[n] = -__expf(A_log[d * DS + n]);
    __syncthreads();

    float Pv[DS], h[DS];
#pragma unroll
    for (int n = 0; n < DS; ++n) { Pv[n] = 1.f; h[n] = 0.f; }

    const u16* dp = delta + (size_t)t0 * DI + d;
    const u16* xp = xs + (size_t)t0 * DI + d;
#pragma unroll 4
    for (int t = 0; t < CH; ++t) {
        float dlt = bf2f(dp[t * DI]);
        float du = dlt * bf2f(xp[t * DI]);
#pragma unroll
        for (int n = 0; n < DS; ++n) {
            float dA = __expf(dlt * An[n]);
            Pv[n] *= dA;
            h[n] = fmaf(dA, h[n], du * sB[t][n]);
        }
    }
    size_t base = ((size_t)(b * NCH + chunk) * DI + d) * DS;
    float4* Pp = (float4*)(P + base);
    float4* Qp = (float4*)(Q + base);
#pragma unroll
    for (int g = 0; g < 4; ++g) {
        Pp[g] = make_float4(Pv[g * 4], Pv[g * 4 + 1], Pv[g * 4 + 2], Pv[g * 4 + 3]);
        Qp[g] = make_float4(h[g * 4], h[g * 4 + 1], h[g * 4 + 2], h[g * 4 + 3]);
    }
}

__global__ __launch_bounds__(256) void scan_pass2(float* __restrict__ P,
                                                  const float* __restrict__ Q)
{
    int tid = blockIdx.x * 256 + threadIdx.x;
    int n = tid & 15;
    int d = (tid >> 4) & (DI - 1);
    int b = tid >> 14;
    float carry = 0.f;
    for (int c = 0; c < NCH; ++c) {
        size_t i = ((size_t)(b * NCH + c) * DI + d) * DS + n;
        float Pv = P[i], Qv = Q[i];
        P[i] = carry;
        carry = fmaf(Pv, carry, Qv);
    }
}

// pass3: re-run from H_in; y = sum_n h_n C_n + D-skip, silu(z) gate -> y bf16
__global__ __launch_bounds__(256) void scan_pass3(
    const u16* __restrict__ delta, const u16* __restrict__ xs,
    const float* __restrict__ dbc, const u16* __restrict__ xz,
    const float* __restrict__ A_log, const float* __restrict__ Dsk,
    const float* __restrict__ Hin, u16* __restrict__ yb)
{
    const int dgrp = blockIdx.x & 3;
    const int chunk = (blockIdx.x >> 2) & (NCH - 1);
    const int b = blockIdx.x >> 7;
    const int d = dgrp * 256 + threadIdx.x;
    const int t0 = b * LL + chunk * CH;

    __shared__ float sBC[CH][32];   // cols 0..15 = B, 16..31 = C
    {
        int i = threadIdx.x;
        int row = i >> 3, col = (i & 7) * 4;
        float4 v = *(const float4*)(dbc + (size_t)(t0 + row) * NX + DTR + col);
        *(float4*)&sBC[row][col] = v;
    }
    float An[DS];
#pragma unroll
    for (int n = 0; n < DS; ++n) An[n] = -__expf(A_log[d * DS + n]);
    const float Dd = Dsk[d];

    float h[DS];
    {
        size_t base = ((size_t)(b * NCH + chunk) * DI + d) * DS;
        const float4* Hp = (const float4*)(Hin + base);
#pragma unroll
        for (int g = 0; g < 4; ++g) {
            float4 v = Hp[g];
            h[g * 4] = v.x; h[g * 4 + 1] = v.y; h[g * 4 + 2] = v.z; h[g * 4 + 3] = v.w;
        }
    }
    __syncthreads();

    const u16* dp = delta + (size_t)t0 * DI + d;
    const u16* xp = xs + (size_t)t0 * DI + d;
    const u16* zp = xz + (size_t)t0 * 2048 + DI + d;
    u16* yp = yb + (size_t)t0 * DI + d;

#pragma unroll 4
    for (int t = 0; t < CH; ++t) {
        float dlt = bf2f(dp[t * DI]);
        float xv  = bf2f(xp[t * DI]);
        float zv  = bf2f(zp[t * 2048]);
        float du = dlt * xv;
        float y = 0.f;
#pragma unroll
        for (int n = 0; n < DS; ++n) {
            float dA = __expf(dlt * An[n]);
            h[n] = fmaf(dA, h[n], du * sBC[t][n]);
            y = fmaf(h[n], sBC[t][DS + n], y);
        }
        y += xv * Dd;
        float sz = zv / (1.f + __expf(-zv));
        yp[t * DI] = f2bf(y * sz);
    }
}

// ---------------------------------------------------------------------------
// residual add + LayerNorm; writes f32 hout; optionally bf16 copy (next GEMM A)
__global__ __launch_bounds__(512) void ln_kernel(
    const float* __restrict__ o, const float* __restrict__ hprev,
    const float* __restrict__ g, const float* __restrict__ bta,
    float* __restrict__ hout, u16* __restrict__ hbf, int wb)
{
    int row = blockIdx.x, c = threadIdx.x;
    size_t off = (size_t)row * DM + c;
    float v = o[off] + hprev[off];
    float s1 = v, s2 = v * v;
#pragma unroll
    for (int m = 32; m >= 1; m >>= 1) {
        s1 += __shfl_xor(s1, m);
        s2 += __shfl_xor(s2, m);
    }
    __shared__ float r1[8], r2[8];
    __shared__ float stats[2];
    int w = c >> 6;
    if ((c & 63) == 0) { r1[w] = s1; r2[w] = s2; }
    __syncthreads();
    if (c == 0) {
        float a = 0.f, q = 0.f;
        for (int i = 0; i < 8; ++i) { a += r1[i]; q += r2[i]; }
        float mean = a / (float)DM;
        float var = q / (float)DM - mean * mean;
        stats[0] = mean;
        stats[1] = rsqrtf(var + 1e-5f);
    }
    __syncthreads();
    float res = (v - stats[0]) * stats[1] * g[c] + bta[c];
    hout[off] = res;
    if (wb) hbf[off] = f2bf(res);
}

// ---------------------------------------------------------------------------
extern "C" void kernel_launch(void* const* d_in, const int* in_sizes, int n_in,
                              void* d_out, int out_size, void* d_ws, size_t ws_size,
                              hipStream_t stream)
{
    const float* x    = (const float*)d_in[0];
    const float* Wi   = (const float*)d_in[1];
    const float* cw   = (const float*)d_in[2];
    const float* cb   = (const float*)d_in[3];
    const float* Wx   = (const float*)d_in[4];
    const float* Wdt  = (const float*)d_in[5];
    const float* bdt  = (const float*)d_in[6];
    const float* Alog = (const float*)d_in[7];
    const float* Dsk  = (const float*)d_in[8];
    const float* Wo   = (const float*)d_in[9];
    const float* lng  = (const float*)d_in[10];
    const float* lnb  = (const float*)d_in[11];

    // workspace (ws_size = 268 MB; using ~88 MB)
    float* fw   = (float*)d_ws;
    float* h    = fw;                      // 2M f32
    float* ob   = h + 2097152;             // 2M f32
    float* dbc  = ob + 2097152;            // 256K f32
    float* pxp  = dbc + 262144;            // 2M f32 (8 x 4096 x 64)
    float* Pb   = pxp + 2097152;           // 2M f32
    float* Qb   = Pb + 2097152;            // 2M f32
    u16* xzb    = (u16*)(Qb + 2097152);    // 8M u16 (4096 x 2048)
    u16* xsbf   = xzb + 8388608;           // 4M u16
    u16* abf    = xsbf + 4194304;          // 4M u16 (x/h bf16, then y bf16)
    u16* dltb   = abf + 4194304;           // 4M u16
    u16* dbcb   = dltb + 4194304;          // 256K u16
    u16* WiT    = dbcb + 262144;           // 2 x 1M u16
    u16* WoT    = WiT + 2097152;           // 2 x 512K u16
    u16* WxT    = WoT + 1048576;           // 2 x 64K u16
    u16* WdtT   = WxT + 131072;            // 2 x 32K u16

    // one-time per call: x -> bf16, all weights -> [N][K] bf16
    cast_bf16<<<2048, 256, 0, stream>>>((const float4*)x, (ushort4*)abf, 524288);
    wtrans<<<dim3(32, 16, 8), 256, 0, stream>>>(Wi, Wo, Wx, Wdt, WiT, WoT, WxT, WdtT);

    for (int l = 0; l < 2; ++l) {
        const float* hin = (l == 0) ? x : h;
        const u16* WiTl  = WiT  + (size_t)l * 2048 * 512;
        const u16* WoTl  = WoT  + (size_t)l * 512 * 1024;
        const u16* WxTl  = WxT  + (size_t)l * 64 * 1024;
        const u16* WdtTl = WdtT + (size_t)l * 1024 * 32;

        // xz = h @ Wi  (4096 x 2048, K=512) -> bf16
        gemm_pipe<128, 64, 0, u16><<<dim3(32, 32, 1), 256, 0, stream>>>(
            abf, WiTl, xzb, 512, 512, 2048, 512, nullptr);

        // xs = silu(conv(xin) + cb) -> bf16
        conv_silu_kernel<<<4096, 256, 0, stream>>>(
            xzb, cw + (size_t)l * DI * 4, cb + (size_t)l * DI, (ushort4*)xsbf);

        // dbc partials = xs @ Wx  (split-K=8, deterministic) -> f32
        gemm_pipe<128, 64, 0, float><<<dim3(1, 32, 8), 256, 0, stream>>>(
            xsbf, WxTl, pxp, 1024, 1024, 64, 128, nullptr);
        reduce_dbc<<<256, 256, 0, stream>>>(
            (const float4*)pxp, (float4*)dbc, (ushort4*)dbcb);

        // delta = softplus(dbc[:, :32] @ Wdt + bdt)  (K=32) -> bf16
        gemm_pipe<128, 64, 1, u16><<<dim3(16, 32, 1), 256, 0, stream>>>(
            dbcb, WdtTl, dltb, 64, 32, 1024, 32, bdt + (size_t)l * DI);

        // chunk-parallel selective scan -> y bf16 (into abf)
        scan_pass1<<<BB * NCH * 4, 256, 0, stream>>>(
            dltb, xsbf, dbc, Alog + (size_t)l * DI * DS, Pb, Qb);
        scan_pass2<<<256, 256, 0, stream>>>(Pb, Qb);
        scan_pass3<<<BB * NCH * 4, 256, 0, stream>>>(
            dltb, xsbf, dbc, xzb, Alog + (size_t)l * DI * DS, Dsk + (size_t)l * DI,
            Pb, abf);

        // o = y @ Wo  (4096 x 512, K=1024) -> f32
        gemm_pipe<64, 64, 0, float><<<dim3(8, 64, 1), 256, 0, stream>>>(
            abf, WoTl, ob, 1024, 1024, 512, 1024, nullptr);

        // h = LN(o + hin); l=0 also writes bf16 h into abf; l=1 -> d_out
        ln_kernel<<<MROWS, 512, 0, stream>>>(
            ob, hin, lng + (size_t)l * DM, lnb + (size_t)l * DM,
            (l == 1) ? (float*)d_out : h, abf, l == 0);
    }
}